// Round 10
// baseline (893.864 us; speedup 1.0000x reference)
//
#include <hip/hip_runtime.h>

#define N_NODES 20000
#define N_EDGES 640000
#define XS 136   // LDS activation row stride in bf16 units (128 + 8 pad)

#define INV_SQRT_AVG 0.0070714082f   // 1/sqrt(19999)
#define INV_AVG      5.000250e-5f    // 1/19999

#define FEATB_OFF 147456             // ushort offset of bf16 feat table in ws (after 9*16384 weights)
#define OUT_FLOATS 2620000

typedef __attribute__((ext_vector_type(8))) short bf16x8;
typedef __attribute__((ext_vector_type(4))) float f32x4;

// wave-internal LDS ordering: wait DS ops, block compiler reordering
#define WAVE_FENCE() asm volatile("s_waitcnt lgkmcnt(0)" ::: "memory")

__device__ __forceinline__ ushort f2b(float f) {
  unsigned x = __float_as_uint(f);
  unsigned r = (x + 0x7fffu + ((x >> 16) & 1u)) >> 16;   // RNE
  return (ushort)r;
}
__device__ __forceinline__ float silu(float v) {
  return v * __builtin_amdgcn_rcpf(1.0f + __expf(-v));
}
__device__ __forceinline__ float sigmoid_fast(float v) {
  return __builtin_amdgcn_rcpf(1.0f + __expf(-v));
}

// ---------------- fused setup: weights f32[k][n]->bf16[n][k]; feat->bf16; zero out ----
struct PrepArgs { const float* src[9]; };

__global__ __launch_bounds__(256) void setup_kernel(PrepArgs a,
                                                    const float* __restrict__ feat,
                                                    ushort* __restrict__ wq,
                                                    ushort* __restrict__ featb,
                                                    float* __restrict__ out) {
  int i = blockIdx.x * 256 + threadIdx.x;
  if (i < OUT_FLOATS) out[i] = 0.0f;
  if (i < N_NODES * 128) featb[i] = f2b(feat[i]);
  if (i < 9 * 16384) {
    int m = i >> 14, idx = i & 16383;
    int k = idx >> 7, n = idx & 127;
    wq[m * 16384 + n * 128 + k] = f2b(a.src[m][k * 128 + n]);
  }
}

// ---------------- per-wave 16x128x128 layer: acc[nt] += X(16x128) * W(128x128) ----
// X: LDS rows r0..r0+15. Wn: global bf16 [n][k]. Output C: col=nt*16+(lane&15), row=q*4+rg.
__device__ __forceinline__ void gemm16(const ushort* X, int r0, const ushort* __restrict__ Wn,
                                       int c, int q, f32x4 acc[8]) {
  const int kq = q * 8;
  bf16x8 a[4];
#pragma unroll
  for (int ks = 0; ks < 4; ++ks)
    a[ks] = *(const bf16x8*)(X + (r0 + c) * XS + ks * 32 + kq);
#pragma unroll
  for (int nt = 0; nt < 8; ++nt)
#pragma unroll
    for (int ks = 0; ks < 4; ++ks) {
      bf16x8 b = *(const bf16x8*)(Wn + (nt * 16 + c) * 128 + ks * 32 + kq);
      acc[nt] = __builtin_amdgcn_mfma_f32_16x16x32_bf16(a[ks], b, acc[nt], 0, 0, 0);
    }
}

__device__ __forceinline__ void zero8(f32x4 acc[8]) {
  const f32x4 z4 = {0.f, 0.f, 0.f, 0.f};
#pragma unroll
  for (int nt = 0; nt < 8; ++nt) acc[nt] = z4;
}

// stage one bf16 row from global into LDS (4 lanes/row, 16B chunks)
__device__ __forceinline__ void stage_copy(ushort* X, const ushort* __restrict__ src,
                                           int row, int sub) {
  const bf16x8* s = (const bf16x8*)src;
  bf16x8* d = (bf16x8*)(X + row * XS);
#pragma unroll
  for (int c2 = 0; c2 < 4; ++c2) d[sub + 4 * c2] = s[sub + 4 * c2];
}

// stage one f32 row (scaled) as bf16 into LDS
__device__ __forceinline__ void stage_cvt(ushort* X, const float* __restrict__ src,
                                          int row, int sub, float scale) {
  const float4* s4 = (const float4*)src + sub * 8;
  uint* d = (uint*)(X + row * XS + sub * 32);
#pragma unroll
  for (int i = 0; i < 8; ++i) {
    float4 v = s4[i];
    d[2 * i]     = (unsigned)f2b(v.x * scale) | ((unsigned)f2b(v.y * scale) << 16);
    d[2 * i + 1] = (unsigned)f2b(v.z * scale) | ((unsigned)f2b(v.w * scale) << 16);
  }
}

// ---------------- edge kernel: one wave owns 16 edges, ZERO block barriers ----
__global__ __launch_bounds__(256, 4) void edge_kernel(
    const float* __restrict__ pos, const ushort* __restrict__ featb,
    const int* __restrict__ snd, const int* __restrict__ rcv,
    const ushort* __restrict__ wq,
    const float* __restrict__ pe_w0, const float* __restrict__ pe_b0,
    const float* __restrict__ pe_b1,
    const float* __restrict__ px_b0, const float* __restrict__ px_b1,
    const float* __restrict__ px_out_w, const float* __restrict__ px_out_b,
    const float* __restrict__ e_w, const float* __restrict__ e_b,
    float* __restrict__ outv, float* __restrict__ outf) {
  __shared__ ushort XA[64 * XS];
  __shared__ ushort XB[64 * XS];
  __shared__ float lenS[64];
  __shared__ float vecS[64][3];
  __shared__ int ercS[64];

  const int tid = threadIdx.x;
  const int lane = tid & 63;
  const int wv = tid >> 6;
  const int r0 = wv * 16;                 // this wave's LDS row base
  const int e0 = blockIdx.x * 64 + r0;    // this wave's global edge base
  const int c = lane & 15, q = lane >> 4;

  if (lane < 16) {
    int s = snd[e0 + lane], r = rcv[e0 + lane];
    ercS[r0 + lane] = r;
    float vx = pos[r * 3 + 0] - pos[s * 3 + 0];
    float vy = pos[r * 3 + 1] - pos[s * 3 + 1];
    float vz = pos[r * 3 + 2] - pos[s * 3 + 2];
    float n2 = vx * vx + vy * vy + vz * vz;
    float L = (n2 > 0.0f) ? sqrtf(n2) : 0.0f;
    vecS[r0 + lane][0] = vx; vecS[r0 + lane][1] = vy; vecS[r0 + lane][2] = vz;
    lenS[r0 + lane] = L;
  }
  {
    int rr = lane >> 2, sub = lane & 3;
    stage_copy(XA, featb + (size_t)snd[e0 + rr] * 128, r0 + rr, sub);
    stage_copy(XB, featb + (size_t)rcv[e0 + rr] * 128, r0 + rr, sub);
  }
  WAVE_FENCE();

  int rowr[4];
  float lenr[4];
#pragma unroll
  for (int rg = 0; rg < 4; ++rg) {
    rowr[rg] = r0 + q * 4 + rg;
    lenr[rg] = lenS[rowr[rg]];
  }

  f32x4 acc[8];
  // ---- phi_e layer 0: sender + receiver halves ----
  zero8(acc);
  gemm16(XA, r0, wq + 0 * 16384, c, q, acc);
  gemm16(XB, r0, wq + 1 * 16384, c, q, acc);
  WAVE_FENCE();   // done reading XA/XB (own rows) before overwrite below
#pragma unroll
  for (int nt = 0; nt < 8; ++nt) {
    int col = nt * 16 + c;
    float w0 = pe_w0[256 * 128 + col], b0 = pe_b0[col];
#pragma unroll
    for (int rg = 0; rg < 4; ++rg)
      XA[rowr[rg] * XS + col] = f2b(silu(acc[nt][rg] + lenr[rg] * w0 + b0));
  }
  WAVE_FENCE();

  // ---- phi_e layer 1: XA -> m (kept in acc), gate in-wave, m->XB ----
  zero8(acc);
  gemm16(XA, r0, wq + 2 * 16384, c, q, acc);
  float rp[4] = {0.f, 0.f, 0.f, 0.f};
#pragma unroll
  for (int nt = 0; nt < 8; ++nt) {
    int col = nt * 16 + c;
    float b1 = pe_b1[col], ew = e_w[col];
#pragma unroll
    for (int rg = 0; rg < 4; ++rg) {
      float m = silu(acc[nt][rg] + b1);
      acc[nt][rg] = m;
      XB[rowr[rg] * XS + col] = f2b(m);
      rp[rg] += m * ew;
    }
  }
  float eb = e_b[0];
  float eg[4];
  int ercr[4];
#pragma unroll
  for (int rg = 0; rg < 4; ++rg) {
    float s = rp[rg];
    s += __shfl_xor(s, 1); s += __shfl_xor(s, 2);
    s += __shfl_xor(s, 4); s += __shfl_xor(s, 8);
    eg[rg] = sigmoid_fast(s + eb);
    ercr[rg] = ercS[rowr[rg]];
  }
  // gated m_i atomics NOW (coalesced: 4 lines/instr), overlap with phi_x below
#pragma unroll
  for (int nt = 0; nt < 8; ++nt) {
    int col = nt * 16 + c;
#pragma unroll
    for (int rg = 0; rg < 4; ++rg)
      atomicAdd(&outf[(size_t)ercr[rg] * 128 + col], acc[nt][rg] * eg[rg]);
  }
  WAVE_FENCE();   // lgkm only — atomics stay in flight

  // ---- phi_x layer 0: XB -> XA ----
  zero8(acc);
  gemm16(XB, r0, wq + 3 * 16384, c, q, acc);
#pragma unroll
  for (int nt = 0; nt < 8; ++nt) {
    int col = nt * 16 + c;
    float b0 = px_b0[col];
#pragma unroll
    for (int rg = 0; rg < 4; ++rg)
      XA[rowr[rg] * XS + col] = f2b(silu(acc[nt][rg] + b0));
  }
  WAVE_FENCE();

  // ---- phi_x layer 1: XA -> Dense(1) tail, shifts ----
  zero8(acc);
  gemm16(XA, r0, wq + 4 * 16384, c, q, acc);
  float sp[4] = {0.f, 0.f, 0.f, 0.f};
#pragma unroll
  for (int nt = 0; nt < 8; ++nt) {
    int col = nt * 16 + c;
    float b1 = px_b1[col], pw = px_out_w[col];
#pragma unroll
    for (int rg = 0; rg < 4; ++rg)
      sp[rg] += silu(acc[nt][rg] + b1) * pw;
  }
  float pxb = px_out_b[0];
#pragma unroll
  for (int rg = 0; rg < 4; ++rg) {
    float s = sp[rg];
    s += __shfl_xor(s, 1); s += __shfl_xor(s, 2);
    s += __shfl_xor(s, 4); s += __shfl_xor(s, 8);
    if (c < 3) {
      int row = rowr[rg];
      float sh = (s + pxb) * vecS[row][c] * __builtin_amdgcn_rcpf(1.0f + lenS[row]);
      atomicAdd(&outv[(size_t)ercr[rg] * 3 + c], sh);
    }
  }
}

// ---------------- node kernel (unchanged r8 structure) ----------------
__global__ __launch_bounds__(256, 4) void node_kernel(
    const float* __restrict__ pos, const float* __restrict__ feat,
    const ushort* __restrict__ featb, const ushort* __restrict__ wq,
    const float* __restrict__ ph_b0, const float* __restrict__ ph_b1,
    const float* __restrict__ ph_b2,
    float* __restrict__ outv, float* __restrict__ outf) {
  __shared__ ushort XA[64 * XS];
  __shared__ ushort XB[64 * XS];

  const int tid = threadIdx.x;
  const int nb0 = blockIdx.x * 64;
  const int lane = tid & 63;
  const int wv = tid >> 6;
  const int c = lane & 15, q = lane >> 4;
  const int n0 = wv * 32;
  const int col0 = n0 + c, col1 = col0 + 16;

  {
    int row = tid >> 2, sub = tid & 3;
    int nn = nb0 + row; if (nn >= N_NODES) nn = N_NODES - 1;
    stage_cvt(XA, outf + (size_t)nn * 128, row, sub, INV_SQRT_AVG);  // m_i
    stage_copy(XB, featb + (size_t)nn * 128, row, sub);
  }
  __syncthreads();

  const f32x4 z4 = {0.f, 0.f, 0.f, 0.f};
  f32x4 acc[4][2];
#pragma unroll
  for (int mt = 0; mt < 4; ++mt) { acc[mt][0] = z4; acc[mt][1] = z4; }

  const int kq = q * 8;
  // ---- ph layer 0: [m_i | feat] ----
#pragma unroll
  for (int half = 0; half < 2; ++half) {
    const ushort* X = half ? XB : XA;
    const ushort* Wn0 = wq + (5 + half) * 16384 + n0 * 128;
    bf16x8 b[2][4];
#pragma unroll
    for (int ct = 0; ct < 2; ++ct)
#pragma unroll
      for (int ks = 0; ks < 4; ++ks)
        b[ct][ks] = *(const bf16x8*)(Wn0 + (ct * 16 + c) * 128 + ks * 32 + kq);
#pragma unroll
    for (int mt = 0; mt < 4; ++mt)
#pragma unroll
      for (int ks = 0; ks < 4; ++ks) {
        bf16x8 a = *(const bf16x8*)(X + (mt * 16 + c) * XS + ks * 32 + kq);
        acc[mt][0] = __builtin_amdgcn_mfma_f32_16x16x32_bf16(a, b[0][ks], acc[mt][0], 0, 0, 0);
        acc[mt][1] = __builtin_amdgcn_mfma_f32_16x16x32_bf16(a, b[1][ks], acc[mt][1], 0, 0, 0);
      }
  }
  __syncthreads();
  {
    float b0 = ph_b0[col0], b1 = ph_b0[col1];
#pragma unroll
    for (int mt = 0; mt < 4; ++mt)
#pragma unroll
      for (int rg = 0; rg < 4; ++rg) {
        int row = mt * 16 + q * 4 + rg;
        XA[row * XS + col0] = f2b(silu(acc[mt][0][rg] + b0));
        XA[row * XS + col1] = f2b(silu(acc[mt][1][rg] + b1));
      }
  }
  __syncthreads();

  // ---- ph layer 1: XA -> XB ----
#pragma unroll
  for (int mt = 0; mt < 4; ++mt) { acc[mt][0] = z4; acc[mt][1] = z4; }
  {
    const ushort* Wn0 = wq + 7 * 16384 + n0 * 128;
    bf16x8 b[2][4];
#pragma unroll
    for (int ct = 0; ct < 2; ++ct)
#pragma unroll
      for (int ks = 0; ks < 4; ++ks)
        b[ct][ks] = *(const bf16x8*)(Wn0 + (ct * 16 + c) * 128 + ks * 32 + kq);
#pragma unroll
    for (int mt = 0; mt < 4; ++mt)
#pragma unroll
      for (int ks = 0; ks < 4; ++ks) {
        bf16x8 a = *(const bf16x8*)(XA + (mt * 16 + c) * XS + ks * 32 + kq);
        acc[mt][0] = __builtin_amdgcn_mfma_f32_16x16x32_bf16(a, b[0][ks], acc[mt][0], 0, 0, 0);
        acc[mt][1] = __builtin_amdgcn_mfma_f32_16x16x32_bf16(a, b[1][ks], acc[mt][1], 0, 0, 0);
      }
  }
  __syncthreads();
  {
    float b0 = ph_b1[col0], b1 = ph_b1[col1];
#pragma unroll
    for (int mt = 0; mt < 4; ++mt)
#pragma unroll
      for (int rg = 0; rg < 4; ++rg) {
        int row = mt * 16 + q * 4 + rg;
        XB[row * XS + col0] = f2b(silu(acc[mt][0][rg] + b0));
        XB[row * XS + col1] = f2b(silu(acc[mt][1][rg] + b1));
      }
  }
  __syncthreads();

  // ---- ph layer 2 (no act) + residual ----
#pragma unroll
  for (int mt = 0; mt < 4; ++mt) { acc[mt][0] = z4; acc[mt][1] = z4; }
  {
    const ushort* Wn0 = wq + 8 * 16384 + n0 * 128;
    bf16x8 b[2][4];
#pragma unroll
    for (int ct = 0; ct < 2; ++ct)
#pragma unroll
      for (int ks = 0; ks < 4; ++ks)
        b[ct][ks] = *(const bf16x8*)(Wn0 + (ct * 16 + c) * 128 + ks * 32 + kq);
#pragma unroll
    for (int mt = 0; mt < 4; ++mt)
#pragma unroll
      for (int ks = 0; ks < 4; ++ks) {
        bf16x8 a = *(const bf16x8*)(XB + (mt * 16 + c) * XS + ks * 32 + kq);
        acc[mt][0] = __builtin_amdgcn_mfma_f32_16x16x32_bf16(a, b[0][ks], acc[mt][0], 0, 0, 0);
        acc[mt][1] = __builtin_amdgcn_mfma_f32_16x16x32_bf16(a, b[1][ks], acc[mt][1], 0, 0, 0);
      }
  }
  {
    float b0 = ph_b2[col0], b1 = ph_b2[col1];
#pragma unroll
    for (int mt = 0; mt < 4; ++mt)
#pragma unroll
      for (int rg = 0; rg < 4; ++rg) {
        int row = mt * 16 + q * 4 + rg;
        int nn = nb0 + row;
        if (nn < N_NODES) {
          size_t o = (size_t)nn * 128;
          outf[o + col0] = acc[mt][0][rg] + b0 + feat[o + col0];
          outf[o + col1] = acc[mt][1][rg] + b1 + feat[o + col1];
        }
      }
  }
  if (tid < 192) {
    int nl = tid / 3, cc = tid - nl * 3;
    int nn = nb0 + nl;
    if (nn < N_NODES)
      outv[nn * 3 + cc] = pos[nn * 3 + cc] + outv[nn * 3 + cc] * INV_AVG;
  }
}

// ---------------- launch ----------------
extern "C" void kernel_launch(void* const* d_in, const int* in_sizes, int n_in,
                              void* d_out, int out_size, void* d_ws, size_t ws_size,
                              hipStream_t stream) {
  const float* pos  = (const float*)d_in[0];
  const float* feat = (const float*)d_in[1];
  const float* pe_w0 = (const float*)d_in[2];
  const float* pe_b0 = (const float*)d_in[3];
  const float* pe_b1 = (const float*)d_in[5];
  const float* px_b0 = (const float*)d_in[7];
  const float* px_b1 = (const float*)d_in[9];
  const float* px_out_w = (const float*)d_in[10];
  const float* px_out_b = (const float*)d_in[11];
  const float* e_w = (const float*)d_in[12];
  const float* e_b = (const float*)d_in[13];
  const float* ph_b0 = (const float*)d_in[15];
  const float* ph_b1 = (const float*)d_in[17];
  const float* ph_b2 = (const float*)d_in[19];
  const int* snd = (const int*)d_in[20];
  const int* rcv = (const int*)d_in[21];
  ushort* wq = (ushort*)d_ws;
  ushort* featb = wq + FEATB_OFF;
  float* out = (float*)d_out;

  PrepArgs a;
  a.src[0] = pe_w0;
  a.src[1] = pe_w0 + 128 * 128;
  a.src[2] = (const float*)d_in[4];               // pe_w1
  a.src[3] = (const float*)d_in[6];               // px_w0
  a.src[4] = (const float*)d_in[8];               // px_w1
  a.src[5] = (const float*)d_in[14];              // ph_w0 (m_i half)
  a.src[6] = (const float*)d_in[14] + 128 * 128;  // ph_w0 (feat half)
  a.src[7] = (const float*)d_in[16];              // ph_w1
  a.src[8] = (const float*)d_in[18];              // ph_w2

  setup_kernel<<<(OUT_FLOATS + 255) / 256, 256, 0, stream>>>(a, feat, wq, featb, out);

  edge_kernel<<<N_EDGES / 64, 256, 0, stream>>>(
      pos, featb, snd, rcv, wq,
      pe_w0, pe_b0, pe_b1, px_b0, px_b1,
      px_out_w, px_out_b, e_w, e_b,
      out, out + 60000);

  node_kernel<<<(N_NODES + 63) / 64, 256, 0, stream>>>(
      pos, feat, featb, wq, ph_b0, ph_b1, ph_b2,
      out, out + 60000);
}

// Round 11
// 504.003 us; speedup vs baseline: 1.7735x; 1.7735x over previous
//
#include <hip/hip_runtime.h>

#define N_NODES 20000
#define N_EDGES 640000
#define XS 136   // LDS activation row stride in bf16 units (128 + 8 pad)

#define INV_SQRT_AVG 0.0070714082f   // 1/sqrt(19999)
#define INV_AVG      5.000250e-5f    // 1/19999

#define FEATB_OFF 147456             // ushort offset of bf16 feat table in ws (after 9*16384 weights)
#define OUT_FLOATS 2620000

typedef __attribute__((ext_vector_type(8))) short bf16x8;
typedef __attribute__((ext_vector_type(4))) float f32x4;

// Non-draining barrier: LDS ordering only. Correct here because (a) all
// cross-wave communication in these kernels is through LDS (lgkmcnt), and
// (b) global atomics are never read back within the kernel, (c) staged
// global->LDS data is ordered by the compiler's data-dependent vmcnt waits
// before the ds_write. Avoids the s_waitcnt vmcnt(0) atomic/load drain that
// __syncthreads() would impose on every wave at every barrier.
#define BAR() asm volatile("s_waitcnt lgkmcnt(0)\n\ts_barrier" ::: "memory")

__device__ __forceinline__ ushort f2b(float f) {
  unsigned x = __float_as_uint(f);
  unsigned r = (x + 0x7fffu + ((x >> 16) & 1u)) >> 16;   // RNE
  return (ushort)r;
}
// fast silu: raw v_rcp_f32 (1 ulp) instead of IEEE division sequence
__device__ __forceinline__ float silu(float v) {
  return v * __builtin_amdgcn_rcpf(1.0f + __expf(-v));
}
__device__ __forceinline__ float sigmoid_fast(float v) {
  return __builtin_amdgcn_rcpf(1.0f + __expf(-v));
}

// ---------------- fused setup: weights f32[k][n]->bf16[n][k]; feat->bf16; zero out ----
struct PrepArgs { const float* src[9]; };

__global__ __launch_bounds__(256) void setup_kernel(PrepArgs a,
                                                    const float* __restrict__ feat,
                                                    ushort* __restrict__ wq,
                                                    ushort* __restrict__ featb,
                                                    float* __restrict__ out) {
  int i = blockIdx.x * 256 + threadIdx.x;
  if (i < OUT_FLOATS) out[i] = 0.0f;
  if (i < N_NODES * 128) featb[i] = f2b(feat[i]);
  if (i < 9 * 16384) {
    int m = i >> 14, idx = i & 16383;
    int k = idx >> 7, n = idx & 127;
    wq[m * 16384 + n * 128 + k] = f2b(a.src[m][k * 128 + n]);
  }
}

// ---------------- MFMA 64x32x128 per wave ----------------
__device__ __forceinline__ void gemm2(const ushort* X, const ushort* __restrict__ Wn0,
                                      int c, int q, f32x4 acc[4][2]) {
  const int kq = q * 8;
  bf16x8 b[2][4];
#pragma unroll
  for (int ct = 0; ct < 2; ++ct)
#pragma unroll
    for (int ks = 0; ks < 4; ++ks)
      b[ct][ks] = *(const bf16x8*)(Wn0 + (ct * 16 + c) * 128 + ks * 32 + kq);
#pragma unroll
  for (int mt = 0; mt < 4; ++mt)
#pragma unroll
    for (int ks = 0; ks < 4; ++ks) {
      bf16x8 a = *(const bf16x8*)(X + (mt * 16 + c) * XS + ks * 32 + kq);
      acc[mt][0] = __builtin_amdgcn_mfma_f32_16x16x32_bf16(a, b[0][ks], acc[mt][0], 0, 0, 0);
      acc[mt][1] = __builtin_amdgcn_mfma_f32_16x16x32_bf16(a, b[1][ks], acc[mt][1], 0, 0, 0);
    }
}

// stage one bf16 row from global into LDS (4 threads/row, 16B chunks)
__device__ __forceinline__ void stage_copy(ushort* X, const ushort* __restrict__ src,
                                           int row, int sub) {
  const bf16x8* s = (const bf16x8*)src;
  bf16x8* d = (bf16x8*)(X + row * XS);
#pragma unroll
  for (int c2 = 0; c2 < 4; ++c2) d[sub + 4 * c2] = s[sub + 4 * c2];
}

// stage one f32 row (scaled) as bf16 into LDS
__device__ __forceinline__ void stage_cvt(ushort* X, const float* __restrict__ src,
                                          int row, int sub, float scale) {
  const float4* s4 = (const float4*)src + sub * 8;
  uint* d = (uint*)(X + row * XS + sub * 32);
#pragma unroll
  for (int i = 0; i < 8; ++i) {
    float4 v = s4[i];
    d[2 * i]     = (unsigned)f2b(v.x * scale) | ((unsigned)f2b(v.y * scale) << 16);
    d[2 * i + 1] = (unsigned)f2b(v.z * scale) | ((unsigned)f2b(v.w * scale) << 16);
  }
}

// ---------------- edge kernel ----------------
__global__ __launch_bounds__(256, 3) void edge_kernel(
    const float* __restrict__ pos, const ushort* __restrict__ featb,
    const int* __restrict__ snd, const int* __restrict__ rcv,
    const ushort* __restrict__ wq,
    const float* __restrict__ pe_w0, const float* __restrict__ pe_b0,
    const float* __restrict__ pe_b1,
    const float* __restrict__ px_b0, const float* __restrict__ px_b1,
    const float* __restrict__ px_out_w, const float* __restrict__ px_out_b,
    const float* __restrict__ e_w, const float* __restrict__ e_b,
    float* __restrict__ outv, float* __restrict__ outf) {
  __shared__ ushort XA[64 * XS];
  __shared__ ushort XB[64 * XS];
  __shared__ float lenf[64], gp[64], pp[64], egl[64];
  __shared__ float vec3[64][3];
  __shared__ int erc[64];

  const int tid = threadIdx.x;
  const int e0 = blockIdx.x * 64;
  const int lane = tid & 63;
  const int wv = tid >> 6;
  const int c = lane & 15, q = lane >> 4;
  const int n0 = wv * 32;
  const int col0 = n0 + c, col1 = col0 + 16;

  if (tid < 64) {
    int s = snd[e0 + tid], r = rcv[e0 + tid];
    erc[tid] = r;
    float vx = pos[r * 3 + 0] - pos[s * 3 + 0];
    float vy = pos[r * 3 + 1] - pos[s * 3 + 1];
    float vz = pos[r * 3 + 2] - pos[s * 3 + 2];
    float n2 = vx * vx + vy * vy + vz * vz;
    float L = (n2 > 0.0f) ? sqrtf(n2) : 0.0f;
    vec3[tid][0] = vx; vec3[tid][1] = vy; vec3[tid][2] = vz;
    lenf[tid] = L; gp[tid] = 0.0f; pp[tid] = 0.0f;
  }
  {
    int row = tid >> 2, sub = tid & 3;
    stage_copy(XA, featb + (size_t)snd[e0 + row] * 128, row, sub);
    stage_copy(XB, featb + (size_t)rcv[e0 + row] * 128, row, sub);
  }
  BAR();

  const f32x4 z4 = {0.f, 0.f, 0.f, 0.f};
  f32x4 acc[4][2];
#pragma unroll
  for (int mt = 0; mt < 4; ++mt) { acc[mt][0] = z4; acc[mt][1] = z4; }

  // ---- phi_e layer 0 ----
  gemm2(XA, wq + 0 * 16384 + n0 * 128, c, q, acc);
  gemm2(XB, wq + 1 * 16384 + n0 * 128, c, q, acc);
  BAR();
  {
    float b0 = pe_b0[col0], b1 = pe_b0[col1];
    float w0 = pe_w0[256 * 128 + col0], w1 = pe_w0[256 * 128 + col1];
#pragma unroll
    for (int mt = 0; mt < 4; ++mt)
#pragma unroll
      for (int rg = 0; rg < 4; ++rg) {
        int row = mt * 16 + q * 4 + rg;
        float L = lenf[row];
        XA[row * XS + col0] = f2b(silu(acc[mt][0][rg] + L * w0 + b0));
        XA[row * XS + col1] = f2b(silu(acc[mt][1][rg] + L * w1 + b1));
      }
  }
  BAR();

  // ---- phi_e layer 1: XA -> m (single silu; keep m in regs across gate barrier) ----
#pragma unroll
  for (int mt = 0; mt < 4; ++mt) { acc[mt][0] = z4; acc[mt][1] = z4; }
  gemm2(XA, wq + 2 * 16384 + n0 * 128, c, q, acc);
  float mreg[4][4][2];
  {
    float b0 = pe_b1[col0], b1 = pe_b1[col1];
    float ew0 = e_w[col0], ew1 = e_w[col1];
#pragma unroll
    for (int mt = 0; mt < 4; ++mt)
#pragma unroll
      for (int rg = 0; rg < 4; ++rg) {
        int row = mt * 16 + q * 4 + rg;
        float m0 = silu(acc[mt][0][rg] + b0);
        float m1 = silu(acc[mt][1][rg] + b1);
        mreg[mt][rg][0] = m0; mreg[mt][rg][1] = m1;
        XB[row * XS + col0] = f2b(m0);
        XB[row * XS + col1] = f2b(m1);
        float rp = m0 * ew0 + m1 * ew1;
        rp += __shfl_xor(rp, 1); rp += __shfl_xor(rp, 2);
        rp += __shfl_xor(rp, 4); rp += __shfl_xor(rp, 8);
        if (c == 0) atomicAdd(&gp[row], rp);
      }
  }
  BAR();
  if (tid < 64) egl[tid] = sigmoid_fast(gp[tid] + e_b[0]);
  BAR();

  // ---- gated m_i atomics, coalesced (16 consecutive lanes per row) ----
#pragma unroll
  for (int mt = 0; mt < 4; ++mt)
#pragma unroll
    for (int rg = 0; rg < 4; ++rg) {
      int row = mt * 16 + q * 4 + rg;
      float eg = egl[row];
      size_t rb = (size_t)erc[row] * 128;
      atomicAdd(&outf[rb + col0], mreg[mt][rg][0] * eg);
      atomicAdd(&outf[rb + col1], mreg[mt][rg][1] * eg);
    }

  // ---- phi_x layer 0: XB -> XA (atomics above stay in flight; no vmcnt drain) ----
#pragma unroll
  for (int mt = 0; mt < 4; ++mt) { acc[mt][0] = z4; acc[mt][1] = z4; }
  gemm2(XB, wq + 3 * 16384 + n0 * 128, c, q, acc);
  {
    float b0 = px_b0[col0], b1 = px_b0[col1];
#pragma unroll
    for (int mt = 0; mt < 4; ++mt)
#pragma unroll
      for (int rg = 0; rg < 4; ++rg) {
        int row = mt * 16 + q * 4 + rg;
        XA[row * XS + col0] = f2b(silu(acc[mt][0][rg] + b0));
        XA[row * XS + col1] = f2b(silu(acc[mt][1][rg] + b1));
      }
  }
  BAR();

  // ---- phi_x layer 1: XA -> Dense(1) tail ----
#pragma unroll
  for (int mt = 0; mt < 4; ++mt) { acc[mt][0] = z4; acc[mt][1] = z4; }
  gemm2(XA, wq + 4 * 16384 + n0 * 128, c, q, acc);
  {
    float b0 = px_b1[col0], b1 = px_b1[col1];
    float pw0 = px_out_w[col0], pw1 = px_out_w[col1];
#pragma unroll
    for (int mt = 0; mt < 4; ++mt)
#pragma unroll
      for (int rg = 0; rg < 4; ++rg) {
        float rp = silu(acc[mt][0][rg] + b0) * pw0 + silu(acc[mt][1][rg] + b1) * pw1;
        rp += __shfl_xor(rp, 1); rp += __shfl_xor(rp, 2);
        rp += __shfl_xor(rp, 4); rp += __shfl_xor(rp, 8);
        if (c == 0) atomicAdd(&pp[mt * 16 + q * 4 + rg], rp);
      }
  }
  BAR();
  if (tid < 192) {
    int ee = tid / 3, cc = tid - ee * 3;
    float phi = pp[ee] + px_out_b[0];
    float sh = phi * vec3[ee][cc] * __builtin_amdgcn_rcpf(1.0f + lenf[ee]);
    atomicAdd(&outv[(size_t)erc[ee] * 3 + cc], sh);
  }
}

// ---------------- node kernel ----------------
__global__ __launch_bounds__(256, 3) void node_kernel(
    const float* __restrict__ pos, const float* __restrict__ feat,
    const ushort* __restrict__ featb, const ushort* __restrict__ wq,
    const float* __restrict__ ph_b0, const float* __restrict__ ph_b1,
    const float* __restrict__ ph_b2,
    float* __restrict__ outv, float* __restrict__ outf) {
  __shared__ ushort XA[64 * XS];
  __shared__ ushort XB[64 * XS];

  const int tid = threadIdx.x;
  const int nb0 = blockIdx.x * 64;
  const int lane = tid & 63;
  const int wv = tid >> 6;
  const int c = lane & 15, q = lane >> 4;
  const int n0 = wv * 32;
  const int col0 = n0 + c, col1 = col0 + 16;

  {
    int row = tid >> 2, sub = tid & 3;
    int nn = nb0 + row; if (nn >= N_NODES) nn = N_NODES - 1;
    stage_cvt(XA, outf + (size_t)nn * 128, row, sub, INV_SQRT_AVG);  // m_i
    stage_copy(XB, featb + (size_t)nn * 128, row, sub);
  }
  BAR();

  const f32x4 z4 = {0.f, 0.f, 0.f, 0.f};
  f32x4 acc[4][2];
#pragma unroll
  for (int mt = 0; mt < 4; ++mt) { acc[mt][0] = z4; acc[mt][1] = z4; }

  // ---- ph layer 0: [m_i | feat] ----
  gemm2(XA, wq + 5 * 16384 + n0 * 128, c, q, acc);
  gemm2(XB, wq + 6 * 16384 + n0 * 128, c, q, acc);
  BAR();
  {
    float b0 = ph_b0[col0], b1 = ph_b0[col1];
#pragma unroll
    for (int mt = 0; mt < 4; ++mt)
#pragma unroll
      for (int rg = 0; rg < 4; ++rg) {
        int row = mt * 16 + q * 4 + rg;
        XA[row * XS + col0] = f2b(silu(acc[mt][0][rg] + b0));
        XA[row * XS + col1] = f2b(silu(acc[mt][1][rg] + b1));
      }
  }
  BAR();

  // ---- ph layer 1: XA -> XB ----
#pragma unroll
  for (int mt = 0; mt < 4; ++mt) { acc[mt][0] = z4; acc[mt][1] = z4; }
  gemm2(XA, wq + 7 * 16384 + n0 * 128, c, q, acc);
  BAR();
  {
    float b0 = ph_b1[col0], b1 = ph_b1[col1];
#pragma unroll
    for (int mt = 0; mt < 4; ++mt)
#pragma unroll
      for (int rg = 0; rg < 4; ++rg) {
        int row = mt * 16 + q * 4 + rg;
        XB[row * XS + col0] = f2b(silu(acc[mt][0][rg] + b0));
        XB[row * XS + col1] = f2b(silu(acc[mt][1][rg] + b1));
      }
  }
  BAR();

  // ---- ph layer 2 (no act) + residual ----
#pragma unroll
  for (int mt = 0; mt < 4; ++mt) { acc[mt][0] = z4; acc[mt][1] = z4; }
  gemm2(XB, wq + 8 * 16384 + n0 * 128, c, q, acc);
  {
    float b0 = ph_b2[col0], b1 = ph_b2[col1];
#pragma unroll
    for (int mt = 0; mt < 4; ++mt)
#pragma unroll
      for (int rg = 0; rg < 4; ++rg) {
        int row = mt * 16 + q * 4 + rg;
        int nn = nb0 + row;
        if (nn < N_NODES) {
          size_t o = (size_t)nn * 128;
          outf[o + col0] = acc[mt][0][rg] + b0 + feat[o + col0];
          outf[o + col1] = acc[mt][1][rg] + b1 + feat[o + col1];
        }
      }
  }
  if (tid < 192) {
    int nl = tid / 3, cc = tid - nl * 3;
    int nn = nb0 + nl;
    if (nn < N_NODES)
      outv[nn * 3 + cc] = pos[nn * 3 + cc] + outv[nn * 3 + cc] * INV_AVG;
  }
}

// ---------------- launch ----------------
extern "C" void kernel_launch(void* const* d_in, const int* in_sizes, int n_in,
                              void* d_out, int out_size, void* d_ws, size_t ws_size,
                              hipStream_t stream) {
  const float* pos  = (const float*)d_in[0];
  const float* feat = (const float*)d_in[1];
  const float* pe_w0 = (const float*)d_in[2];
  const float* pe_b0 = (const float*)d_in[3];
  const float* pe_b1 = (const float*)d_in[5];
  const float* px_b0 = (const float*)d_in[7];
  const float* px_b1 = (const float*)d_in[9];
  const float* px_out_w = (const float*)d_in[10];
  const float* px_out_b = (const float*)d_in[11];
  const float* e_w = (const float*)d_in[12];
  const float* e_b = (const float*)d_in[13];
  const float* ph_b0 = (const float*)d_in[15];
  const float* ph_b1 = (const float*)d_in[17];
  const float* ph_b2 = (const float*)d_in[19];
  const int* snd = (const int*)d_in[20];
  const int* rcv = (const int*)d_in[21];
  ushort* wq = (ushort*)d_ws;
  ushort* featb = wq + FEATB_OFF;
  float* out = (float*)d_out;

  PrepArgs a;
  a.src[0] = pe_w0;
  a.src[1] = pe_w0 + 128 * 128;
  a.src[2] = (const float*)d_in[4];               // pe_w1
  a.src[3] = (const float*)d_in[6];               // px_w0
  a.src[4] = (const float*)d_in[8];               // px_w1
  a.src[5] = (const float*)d_in[14];              // ph_w0 (m_i half)
  a.src[6] = (const float*)d_in[14] + 128 * 128;  // ph_w0 (feat half)
  a.src[7] = (const float*)d_in[16];              // ph_w1
  a.src[8] = (const float*)d_in[18];              // ph_w2

  // one fused setup launch: weight cvt + feat cvt + zero d_out (accumulators)
  setup_kernel<<<(OUT_FLOATS + 255) / 256, 256, 0, stream>>>(a, feat, wq, featb, out);

  edge_kernel<<<N_EDGES / 64, 256, 0, stream>>>(
      pos, featb, snd, rcv, wq,
      pe_w0, pe_b0, pe_b1, px_b0, px_b1,
      px_out_w, px_out_b, e_w, e_b,
      out, out + 60000);

  node_kernel<<<(N_NODES + 63) / 64, 256, 0, stream>>>(
      pos, feat, featb, wq, ph_b0, ph_b1, ph_b2,
      out, out + 60000);
}

// Round 12
// 499.108 us; speedup vs baseline: 1.7909x; 1.0098x over previous
//
#include <hip/hip_runtime.h>

#define N_NODES 20000
#define N_EDGES 640000
#define XS 136   // LDS activation row stride in bf16 units (128 + 8 pad)

#define INV_SQRT_AVG 0.0070714082f   // 1/sqrt(19999)
#define INV_AVG      5.000250e-5f    // 1/19999

#define FEATB_OFF 147456             // ushort offset of bf16 feat table in ws (after 9*16384 weights)
#define OUT_FLOATS 2620000

typedef __attribute__((ext_vector_type(8))) short bf16x8;
typedef __attribute__((ext_vector_type(4))) float f32x4;

// Non-draining barrier: LDS ordering only (proven neutral-correct in r11).
#define BAR() asm volatile("s_waitcnt lgkmcnt(0)\n\ts_barrier" ::: "memory")

__device__ __forceinline__ ushort f2b(float f) {
  unsigned x = __float_as_uint(f);
  unsigned r = (x + 0x7fffu + ((x >> 16) & 1u)) >> 16;   // RNE
  return (ushort)r;
}
__device__ __forceinline__ float silu(float v) {
  return v * __builtin_amdgcn_rcpf(1.0f + __expf(-v));
}
__device__ __forceinline__ float sigmoid_fast(float v) {
  return __builtin_amdgcn_rcpf(1.0f + __expf(-v));
}

// ---------------- fused setup: weights f32[k][n]->bf16[n][k]; feat->bf16; zero out ----
struct PrepArgs { const float* src[9]; };

__global__ __launch_bounds__(256) void setup_kernel(PrepArgs a,
                                                    const float* __restrict__ feat,
                                                    ushort* __restrict__ wq,
                                                    ushort* __restrict__ featb,
                                                    float* __restrict__ out) {
  int i = blockIdx.x * 256 + threadIdx.x;
  if (i < OUT_FLOATS) out[i] = 0.0f;
  if (i < N_NODES * 128) featb[i] = f2b(feat[i]);
  if (i < 9 * 16384) {
    int m = i >> 14, idx = i & 16383;
    int k = idx >> 7, n = idx & 127;
    wq[m * 16384 + n * 128 + k] = f2b(a.src[m][k * 128 + n]);
  }
}

// ---------------- MFMA 64x32x128 per wave ----------------
__device__ __forceinline__ void gemm2(const ushort* X, const ushort* __restrict__ Wn0,
                                      int c, int q, f32x4 acc[4][2]) {
  const int kq = q * 8;
  bf16x8 b[2][4];
#pragma unroll
  for (int ct = 0; ct < 2; ++ct)
#pragma unroll
    for (int ks = 0; ks < 4; ++ks)
      b[ct][ks] = *(const bf16x8*)(Wn0 + (ct * 16 + c) * 128 + ks * 32 + kq);
#pragma unroll
  for (int mt = 0; mt < 4; ++mt)
#pragma unroll
    for (int ks = 0; ks < 4; ++ks) {
      bf16x8 a = *(const bf16x8*)(X + (mt * 16 + c) * XS + ks * 32 + kq);
      acc[mt][0] = __builtin_amdgcn_mfma_f32_16x16x32_bf16(a, b[0][ks], acc[mt][0], 0, 0, 0);
      acc[mt][1] = __builtin_amdgcn_mfma_f32_16x16x32_bf16(a, b[1][ks], acc[mt][1], 0, 0, 0);
    }
}

// stage one bf16 row from global into LDS (4 threads/row, 16B chunks)
__device__ __forceinline__ void stage_copy(ushort* X, const ushort* __restrict__ src,
                                           int row, int sub) {
  const bf16x8* s = (const bf16x8*)src;
  bf16x8* d = (bf16x8*)(X + row * XS);
#pragma unroll
  for (int c2 = 0; c2 < 4; ++c2) d[sub + 4 * c2] = s[sub + 4 * c2];
}

// stage one f32 row (scaled) as bf16 into LDS
__device__ __forceinline__ void stage_cvt(ushort* X, const float* __restrict__ src,
                                          int row, int sub, float scale) {
  const float4* s4 = (const float4*)src + sub * 8;
  uint* d = (uint*)(X + row * XS + sub * 32);
#pragma unroll
  for (int i = 0; i < 8; ++i) {
    float4 v = s4[i];
    d[2 * i]     = (unsigned)f2b(v.x * scale) | ((unsigned)f2b(v.y * scale) << 16);
    d[2 * i + 1] = (unsigned)f2b(v.z * scale) | ((unsigned)f2b(v.w * scale) << 16);
  }
}

// ---------------- edge kernel: SINGLE activation buffer, ~19.4 KB LDS/block ----
__global__ __launch_bounds__(256, 5) void edge_kernel(
    const float* __restrict__ pos, const ushort* __restrict__ featb,
    const int* __restrict__ snd, const int* __restrict__ rcv,
    const ushort* __restrict__ wq,
    const float* __restrict__ pe_w0, const float* __restrict__ pe_b0,
    const float* __restrict__ pe_b1,
    const float* __restrict__ px_b0, const float* __restrict__ px_b1,
    const float* __restrict__ px_out_w, const float* __restrict__ px_out_b,
    const float* __restrict__ e_w, const float* __restrict__ e_b,
    float* __restrict__ outv, float* __restrict__ outf) {
  __shared__ ushort XA[64 * XS];
  __shared__ float lenf[64], gp[64], pp[64], egl[64];
  __shared__ float vec3[64][3];
  __shared__ int erc[64];

  const int tid = threadIdx.x;
  const int e0 = blockIdx.x * 64;
  const int lane = tid & 63;
  const int wv = tid >> 6;
  const int c = lane & 15, q = lane >> 4;
  const int n0 = wv * 32;
  const int col0 = n0 + c, col1 = col0 + 16;

  if (tid < 64) {
    int s = snd[e0 + tid], r = rcv[e0 + tid];
    erc[tid] = r;
    float vx = pos[r * 3 + 0] - pos[s * 3 + 0];
    float vy = pos[r * 3 + 1] - pos[s * 3 + 1];
    float vz = pos[r * 3 + 2] - pos[s * 3 + 2];
    float n2 = vx * vx + vy * vy + vz * vz;
    float L = (n2 > 0.0f) ? sqrtf(n2) : 0.0f;
    vec3[tid][0] = vx; vec3[tid][1] = vy; vec3[tid][2] = vz;
    lenf[tid] = L; gp[tid] = 0.0f; pp[tid] = 0.0f;
  }
  {
    int row = tid >> 2, sub = tid & 3;
    stage_copy(XA, featb + (size_t)snd[e0 + row] * 128, row, sub);
  }
  BAR();

  const f32x4 z4 = {0.f, 0.f, 0.f, 0.f};
  f32x4 acc[4][2];
#pragma unroll
  for (int mt = 0; mt < 4; ++mt) { acc[mt][0] = z4; acc[mt][1] = z4; }

  // ---- phi_e layer 0a: sender half ----
  gemm2(XA, wq + 0 * 16384 + n0 * 128, c, q, acc);
  BAR();   // all waves done reading sender rows
  {
    int row = tid >> 2, sub = tid & 3;
    stage_copy(XA, featb + (size_t)rcv[e0 + row] * 128, row, sub);
  }
  BAR();
  // ---- phi_e layer 0b: receiver half ----
  gemm2(XA, wq + 1 * 16384 + n0 * 128, c, q, acc);
  BAR();   // done reading receiver rows before h0 overwrite
  {
    float b0 = pe_b0[col0], b1 = pe_b0[col1];
    float w0 = pe_w0[256 * 128 + col0], w1 = pe_w0[256 * 128 + col1];
#pragma unroll
    for (int mt = 0; mt < 4; ++mt)
#pragma unroll
      for (int rg = 0; rg < 4; ++rg) {
        int row = mt * 16 + q * 4 + rg;
        float L = lenf[row];
        XA[row * XS + col0] = f2b(silu(acc[mt][0][rg] + L * w0 + b0));
        XA[row * XS + col1] = f2b(silu(acc[mt][1][rg] + L * w1 + b1));
      }
  }
  BAR();

  // ---- phi_e layer 1: XA(h0) -> m (held in acc), gate partials ----
#pragma unroll
  for (int mt = 0; mt < 4; ++mt) { acc[mt][0] = z4; acc[mt][1] = z4; }
  gemm2(XA, wq + 2 * 16384 + n0 * 128, c, q, acc);
  {
    float b0 = pe_b1[col0], b1 = pe_b1[col1];
    float ew0 = e_w[col0], ew1 = e_w[col1];
#pragma unroll
    for (int mt = 0; mt < 4; ++mt)
#pragma unroll
      for (int rg = 0; rg < 4; ++rg) {
        float m0 = silu(acc[mt][0][rg] + b0);
        float m1 = silu(acc[mt][1][rg] + b1);
        acc[mt][0][rg] = m0;   // acc now holds m_ij (f32)
        acc[mt][1][rg] = m1;
        float rp = m0 * ew0 + m1 * ew1;
        rp += __shfl_xor(rp, 1); rp += __shfl_xor(rp, 2);
        rp += __shfl_xor(rp, 4); rp += __shfl_xor(rp, 8);
        if (c == 0) atomicAdd(&gp[mt * 16 + q * 4 + rg], rp);
      }
  }
  BAR();   // all waves done reading h0; gp complete
  // write m -> XA (bf16) while tid<64 computes the gate
  {
#pragma unroll
    for (int mt = 0; mt < 4; ++mt)
#pragma unroll
      for (int rg = 0; rg < 4; ++rg) {
        int row = mt * 16 + q * 4 + rg;
        XA[row * XS + col0] = f2b(acc[mt][0][rg]);
        XA[row * XS + col1] = f2b(acc[mt][1][rg]);
      }
  }
  if (tid < 64) egl[tid] = sigmoid_fast(gp[tid] + e_b[0]);
  BAR();   // m visible + egl visible

  // ---- gated m_i atomics (coalesced; stay in flight past lgkm-only barriers) ----
#pragma unroll
  for (int mt = 0; mt < 4; ++mt)
#pragma unroll
    for (int rg = 0; rg < 4; ++rg) {
      int row = mt * 16 + q * 4 + rg;
      float eg = egl[row];
      size_t rb = (size_t)erc[row] * 128;
      atomicAdd(&outf[rb + col0], acc[mt][0][rg] * eg);
      atomicAdd(&outf[rb + col1], acc[mt][1][rg] * eg);
    }

  // ---- phi_x layer 0: XA(m) -> acc ----
#pragma unroll
  for (int mt = 0; mt < 4; ++mt) { acc[mt][0] = z4; acc[mt][1] = z4; }
  gemm2(XA, wq + 3 * 16384 + n0 * 128, c, q, acc);
  BAR();   // done reading m before px0-act overwrite
  {
    float b0 = px_b0[col0], b1 = px_b0[col1];
#pragma unroll
    for (int mt = 0; mt < 4; ++mt)
#pragma unroll
      for (int rg = 0; rg < 4; ++rg) {
        int row = mt * 16 + q * 4 + rg;
        XA[row * XS + col0] = f2b(silu(acc[mt][0][rg] + b0));
        XA[row * XS + col1] = f2b(silu(acc[mt][1][rg] + b1));
      }
  }
  BAR();

  // ---- phi_x layer 1: XA -> Dense(1) tail ----
#pragma unroll
  for (int mt = 0; mt < 4; ++mt) { acc[mt][0] = z4; acc[mt][1] = z4; }
  gemm2(XA, wq + 4 * 16384 + n0 * 128, c, q, acc);
  {
    float b0 = px_b1[col0], b1 = px_b1[col1];
    float pw0 = px_out_w[col0], pw1 = px_out_w[col1];
#pragma unroll
    for (int mt = 0; mt < 4; ++mt)
#pragma unroll
      for (int rg = 0; rg < 4; ++rg) {
        float rp = silu(acc[mt][0][rg] + b0) * pw0 + silu(acc[mt][1][rg] + b1) * pw1;
        rp += __shfl_xor(rp, 1); rp += __shfl_xor(rp, 2);
        rp += __shfl_xor(rp, 4); rp += __shfl_xor(rp, 8);
        if (c == 0) atomicAdd(&pp[mt * 16 + q * 4 + rg], rp);
      }
  }
  BAR();
  if (tid < 192) {
    int ee = tid / 3, cc = tid - ee * 3;
    float phi = pp[ee] + px_out_b[0];
    float sh = phi * vec3[ee][cc] * __builtin_amdgcn_rcpf(1.0f + lenf[ee]);
    atomicAdd(&outv[(size_t)erc[ee] * 3 + cc], sh);
  }
}

// ---------------- node kernel (r8 structure, two buffers — only 313 blocks) ----------------
__global__ __launch_bounds__(256, 3) void node_kernel(
    const float* __restrict__ pos, const float* __restrict__ feat,
    const ushort* __restrict__ featb, const ushort* __restrict__ wq,
    const float* __restrict__ ph_b0, const float* __restrict__ ph_b1,
    const float* __restrict__ ph_b2,
    float* __restrict__ outv, float* __restrict__ outf) {
  __shared__ ushort XA[64 * XS];
  __shared__ ushort XB[64 * XS];

  const int tid = threadIdx.x;
  const int nb0 = blockIdx.x * 64;
  const int lane = tid & 63;
  const int wv = tid >> 6;
  const int c = lane & 15, q = lane >> 4;
  const int n0 = wv * 32;
  const int col0 = n0 + c, col1 = col0 + 16;

  {
    int row = tid >> 2, sub = tid & 3;
    int nn = nb0 + row; if (nn >= N_NODES) nn = N_NODES - 1;
    stage_cvt(XA, outf + (size_t)nn * 128, row, sub, INV_SQRT_AVG);  // m_i
    stage_copy(XB, featb + (size_t)nn * 128, row, sub);
  }
  BAR();

  const f32x4 z4 = {0.f, 0.f, 0.f, 0.f};
  f32x4 acc[4][2];
#pragma unroll
  for (int mt = 0; mt < 4; ++mt) { acc[mt][0] = z4; acc[mt][1] = z4; }

  // ---- ph layer 0: [m_i | feat] ----
  gemm2(XA, wq + 5 * 16384 + n0 * 128, c, q, acc);
  gemm2(XB, wq + 6 * 16384 + n0 * 128, c, q, acc);
  BAR();
  {
    float b0 = ph_b0[col0], b1 = ph_b0[col1];
#pragma unroll
    for (int mt = 0; mt < 4; ++mt)
#pragma unroll
      for (int rg = 0; rg < 4; ++rg) {
        int row = mt * 16 + q * 4 + rg;
        XA[row * XS + col0] = f2b(silu(acc[mt][0][rg] + b0));
        XA[row * XS + col1] = f2b(silu(acc[mt][1][rg] + b1));
      }
  }
  BAR();

  // ---- ph layer 1: XA -> XB ----
#pragma unroll
  for (int mt = 0; mt < 4; ++mt) { acc[mt][0] = z4; acc[mt][1] = z4; }
  gemm2(XA, wq + 7 * 16384 + n0 * 128, c, q, acc);
  BAR();
  {
    float b0 = ph_b1[col0], b1 = ph_b1[col1];
#pragma unroll
    for (int mt = 0; mt < 4; ++mt)
#pragma unroll
      for (int rg = 0; rg < 4; ++rg) {
        int row = mt * 16 + q * 4 + rg;
        XB[row * XS + col0] = f2b(silu(acc[mt][0][rg] + b0));
        XB[row * XS + col1] = f2b(silu(acc[mt][1][rg] + b1));
      }
  }
  BAR();

  // ---- ph layer 2 (no act) + residual ----
#pragma unroll
  for (int mt = 0; mt < 4; ++mt) { acc[mt][0] = z4; acc[mt][1] = z4; }
  gemm2(XB, wq + 8 * 16384 + n0 * 128, c, q, acc);
  {
    float b0 = ph_b2[col0], b1 = ph_b2[col1];
#pragma unroll
    for (int mt = 0; mt < 4; ++mt)
#pragma unroll
      for (int rg = 0; rg < 4; ++rg) {
        int row = mt * 16 + q * 4 + rg;
        int nn = nb0 + row;
        if (nn < N_NODES) {
          size_t o = (size_t)nn * 128;
          outf[o + col0] = acc[mt][0][rg] + b0 + feat[o + col0];
          outf[o + col1] = acc[mt][1][rg] + b1 + feat[o + col1];
        }
      }
  }
  if (tid < 192) {
    int nl = tid / 3, cc = tid - nl * 3;
    int nn = nb0 + nl;
    if (nn < N_NODES)
      outv[nn * 3 + cc] = pos[nn * 3 + cc] + outv[nn * 3 + cc] * INV_AVG;
  }
}

// ---------------- launch ----------------
extern "C" void kernel_launch(void* const* d_in, const int* in_sizes, int n_in,
                              void* d_out, int out_size, void* d_ws, size_t ws_size,
                              hipStream_t stream) {
  const float* pos  = (const float*)d_in[0];
  const float* feat = (const float*)d_in[1];
  const float* pe_w0 = (const float*)d_in[2];
  const float* pe_b0 = (const float*)d_in[3];
  const float* pe_b1 = (const float*)d_in[5];
  const float* px_b0 = (const float*)d_in[7];
  const float* px_b1 = (const float*)d_in[9];
  const float* px_out_w = (const float*)d_in[10];
  const float* px_out_b = (const float*)d_in[11];
  const float* e_w = (const float*)d_in[12];
  const float* e_b = (const float*)d_in[13];
  const float* ph_b0 = (const float*)d_in[15];
  const float* ph_b1 = (const float*)d_in[17];
  const float* ph_b2 = (const float*)d_in[19];
  const int* snd = (const int*)d_in[20];
  const int* rcv = (const int*)d_in[21];
  ushort* wq = (ushort*)d_ws;
  ushort* featb = wq + FEATB_OFF;
  float* out = (float*)d_out;

  PrepArgs a;
  a.src[0] = pe_w0;
  a.src[1] = pe_w0 + 128 * 128;
  a.src[2] = (const float*)d_in[4];               // pe_w1
  a.src[3] = (const float*)d_in[6];               // px_w0
  a.src[4] = (const float*)d_in[8];               // px_w1
  a.src[5] = (const float*)d_in[14];              // ph_w0 (m_i half)
  a.src[6] = (const float*)d_in[14] + 128 * 128;  // ph_w0 (feat half)
  a.src[7] = (const float*)d_in[16];              // ph_w1
  a.src[8] = (const float*)d_in[18];              // ph_w2

  // one fused setup launch: weight cvt + feat cvt + zero d_out (accumulators)
  setup_kernel<<<(OUT_FLOATS + 255) / 256, 256, 0, stream>>>(a, feat, wq, featb, out);

  edge_kernel<<<N_EDGES / 64, 256, 0, stream>>>(
      pos, featb, snd, rcv, wq,
      pe_w0, pe_b0, pe_b1, px_b0, px_b1,
      px_out_w, px_out_b, e_w, e_b,
      out, out + 60000);

  node_kernel<<<(N_NODES + 63) / 64, 256, 0, stream>>>(
      pos, feat, featb, wq, ph_b0, ph_b1, ph_b2,
      out, out + 60000);
}

// Round 13
// 400.451 us; speedup vs baseline: 2.2321x; 1.2464x over previous
//
#include <hip/hip_runtime.h>

#define N_NODES 20000
#define N_EDGES 640000
#define XS 136   // LDS activation row stride in bf16 units (128 + 8 pad)

#define INV_SQRT_AVG 0.0070714082f   // 1/sqrt(19999)
#define INV_AVG      5.000250e-5f    // 1/19999

#define FEATB_OFF 147456             // ushort offset of bf16 feat table in ws (after 9*16384 weights)

typedef __attribute__((ext_vector_type(8))) short bf16x8;
typedef __attribute__((ext_vector_type(4))) float f32x4;
typedef __attribute__((ext_vector_type(2))) _Float16 f16x2;

// Non-draining barrier: LDS ordering only (proven neutral-correct in r11/r12).
#define BAR() asm volatile("s_waitcnt lgkmcnt(0)\n\ts_barrier" ::: "memory")

__device__ __forceinline__ ushort f2b(float f) {
  unsigned x = __float_as_uint(f);
  unsigned r = (x + 0x7fffu + ((x >> 16) & 1u)) >> 16;   // RNE
  return (ushort)r;
}
__device__ __forceinline__ float silu(float v) {
  return v * __builtin_amdgcn_rcpf(1.0f + __expf(-v));
}
__device__ __forceinline__ float sigmoid_fast(float v) {
  return __builtin_amdgcn_rcpf(1.0f + __expf(-v));
}
__device__ __forceinline__ float lo16f(uint u) {   // f16 low half -> f32
  ushort us = (ushort)(u & 0xffffu);
  _Float16 h; __builtin_memcpy(&h, &us, 2);
  return (float)h;
}
__device__ __forceinline__ float hi16f(uint u) {
  ushort us = (ushort)(u >> 16);
  _Float16 h; __builtin_memcpy(&h, &us, 2);
  return (float)h;
}
// native packed f16 atomic add (global_atomic_pk_add_f16, gfx90a+)
__device__ __forceinline__ void pk_atomic_f16(ushort* p, float x, float y) {
  typedef __attribute__((address_space(1))) f16x2 gf2;
  f16x2 v = {(_Float16)x, (_Float16)y};
  __builtin_amdgcn_global_atomic_fadd_v2f16((gf2*)(unsigned long long)p, v);
}

// ---------------- setup1: weights f32[k][n]->bf16[n][k]; feat->bf16; zero outv ----
struct PrepArgs { const float* src[9]; };

__global__ __launch_bounds__(256) void setup_kernel(PrepArgs a,
                                                    const float* __restrict__ feat,
                                                    ushort* __restrict__ wq,
                                                    ushort* __restrict__ featb,
                                                    float* __restrict__ outv) {
  int i = blockIdx.x * 256 + threadIdx.x;
  if (i < 60000) outv[i] = 0.0f;
  if (i < N_NODES * 128) featb[i] = f2b(feat[i]);
  if (i < 9 * 16384) {
    int m = i >> 14, idx = i & 16383;
    int k = idx >> 7, n = idx & 127;
    wq[m * 16384 + n * 128 + k] = f2b(a.src[m][k * 128 + n]);
  }
}

// ---------------- setup2: zero the f16 m_acc (overlays the consumed feat input) ----
__global__ __launch_bounds__(256) void zero_macc_kernel(uint* __restrict__ m_acc32) {
  int i = blockIdx.x * 256 + threadIdx.x;   // 1.28M uints = 5.12MB
  m_acc32[i] = 0u;
}

// ---------------- MFMA 64x32x128 per wave ----------------
__device__ __forceinline__ void gemm2(const ushort* X, const ushort* __restrict__ Wn0,
                                      int c, int q, f32x4 acc[4][2]) {
  const int kq = q * 8;
  bf16x8 b[2][4];
#pragma unroll
  for (int ct = 0; ct < 2; ++ct)
#pragma unroll
    for (int ks = 0; ks < 4; ++ks)
      b[ct][ks] = *(const bf16x8*)(Wn0 + (ct * 16 + c) * 128 + ks * 32 + kq);
#pragma unroll
  for (int mt = 0; mt < 4; ++mt)
#pragma unroll
    for (int ks = 0; ks < 4; ++ks) {
      bf16x8 a = *(const bf16x8*)(X + (mt * 16 + c) * XS + ks * 32 + kq);
      acc[mt][0] = __builtin_amdgcn_mfma_f32_16x16x32_bf16(a, b[0][ks], acc[mt][0], 0, 0, 0);
      acc[mt][1] = __builtin_amdgcn_mfma_f32_16x16x32_bf16(a, b[1][ks], acc[mt][1], 0, 0, 0);
    }
}

// stage one bf16 row from global into LDS (4 threads/row, 16B chunks)
__device__ __forceinline__ void stage_copy(ushort* X, const ushort* __restrict__ src,
                                           int row, int sub) {
  const bf16x8* s = (const bf16x8*)src;
  bf16x8* d = (bf16x8*)(X + row * XS);
#pragma unroll
  for (int c2 = 0; c2 < 4; ++c2) d[sub + 4 * c2] = s[sub + 4 * c2];
}

// stage one f16 row (scaled) as bf16 into LDS (4 threads/row)
__device__ __forceinline__ void stage_cvt_f16(ushort* X, const ushort* __restrict__ src,
                                              int row, int sub, float scale) {
  const uint4* s4 = (const uint4*)src + sub * 4;   // 4 x 16B = 64B per thread
  uint* d = (uint*)(X + row * XS + sub * 32);
#pragma unroll
  for (int i = 0; i < 4; ++i) {
    uint4 v = s4[i];
    uint u[4] = {v.x, v.y, v.z, v.w};
#pragma unroll
    for (int j = 0; j < 4; ++j) {
      float x = lo16f(u[j]) * scale, y = hi16f(u[j]) * scale;
      d[4 * i + j] = (unsigned)f2b(x) | ((unsigned)f2b(y) << 16);
    }
  }
}

// ---------------- edge kernel: single activation buffer, f16 packed m_i atomics ----
__global__ __launch_bounds__(256, 5) void edge_kernel(
    const float* __restrict__ pos, const ushort* __restrict__ featb,
    const int* __restrict__ snd, const int* __restrict__ rcv,
    const ushort* __restrict__ wq,
    const float* __restrict__ pe_w0, const float* __restrict__ pe_b0,
    const float* __restrict__ pe_b1,
    const float* __restrict__ px_b0, const float* __restrict__ px_b1,
    const float* __restrict__ px_out_w, const float* __restrict__ px_out_b,
    const float* __restrict__ e_w, const float* __restrict__ e_b,
    float* __restrict__ outv, ushort* __restrict__ outm) {
  __shared__ ushort XA[64 * XS];
  __shared__ float lenf[64], gp[64], pp[64], egl[64];
  __shared__ float vec3[64][3];
  __shared__ int erc[64];

  const int tid = threadIdx.x;
  const int e0 = blockIdx.x * 64;
  const int lane = tid & 63;
  const int wv = tid >> 6;
  const int c = lane & 15, q = lane >> 4;
  const int n0 = wv * 32;
  const int col0 = n0 + c, col1 = col0 + 16;

  if (tid < 64) {
    int s = snd[e0 + tid], r = rcv[e0 + tid];
    erc[tid] = r;
    float vx = pos[r * 3 + 0] - pos[s * 3 + 0];
    float vy = pos[r * 3 + 1] - pos[s * 3 + 1];
    float vz = pos[r * 3 + 2] - pos[s * 3 + 2];
    float n2 = vx * vx + vy * vy + vz * vz;
    float L = (n2 > 0.0f) ? sqrtf(n2) : 0.0f;
    vec3[tid][0] = vx; vec3[tid][1] = vy; vec3[tid][2] = vz;
    lenf[tid] = L; gp[tid] = 0.0f; pp[tid] = 0.0f;
  }
  {
    int row = tid >> 2, sub = tid & 3;
    stage_copy(XA, featb + (size_t)snd[e0 + row] * 128, row, sub);
  }
  BAR();

  const f32x4 z4 = {0.f, 0.f, 0.f, 0.f};
  f32x4 acc[4][2];
#pragma unroll
  for (int mt = 0; mt < 4; ++mt) { acc[mt][0] = z4; acc[mt][1] = z4; }

  // ---- phi_e layer 0a: sender half ----
  gemm2(XA, wq + 0 * 16384 + n0 * 128, c, q, acc);
  BAR();
  {
    int row = tid >> 2, sub = tid & 3;
    stage_copy(XA, featb + (size_t)rcv[e0 + row] * 128, row, sub);
  }
  BAR();
  // ---- phi_e layer 0b: receiver half ----
  gemm2(XA, wq + 1 * 16384 + n0 * 128, c, q, acc);
  BAR();
  {
    float b0 = pe_b0[col0], b1 = pe_b0[col1];
    float w0 = pe_w0[256 * 128 + col0], w1 = pe_w0[256 * 128 + col1];
#pragma unroll
    for (int mt = 0; mt < 4; ++mt)
#pragma unroll
      for (int rg = 0; rg < 4; ++rg) {
        int row = mt * 16 + q * 4 + rg;
        float L = lenf[row];
        XA[row * XS + col0] = f2b(silu(acc[mt][0][rg] + L * w0 + b0));
        XA[row * XS + col1] = f2b(silu(acc[mt][1][rg] + L * w1 + b1));
      }
  }
  BAR();

  // ---- phi_e layer 1: XA(h0) -> m, gate partials ----
#pragma unroll
  for (int mt = 0; mt < 4; ++mt) { acc[mt][0] = z4; acc[mt][1] = z4; }
  gemm2(XA, wq + 2 * 16384 + n0 * 128, c, q, acc);
  {
    float b0 = pe_b1[col0], b1 = pe_b1[col1];
    float ew0 = e_w[col0], ew1 = e_w[col1];
#pragma unroll
    for (int mt = 0; mt < 4; ++mt)
#pragma unroll
      for (int rg = 0; rg < 4; ++rg) {
        float m0 = silu(acc[mt][0][rg] + b0);
        float m1 = silu(acc[mt][1][rg] + b1);
        acc[mt][0][rg] = m0;
        acc[mt][1][rg] = m1;
        float rp = m0 * ew0 + m1 * ew1;
        rp += __shfl_xor(rp, 1); rp += __shfl_xor(rp, 2);
        rp += __shfl_xor(rp, 4); rp += __shfl_xor(rp, 8);
        if (c == 0) atomicAdd(&gp[mt * 16 + q * 4 + rg], rp);
      }
  }
  BAR();   // all waves done reading h0; gp complete
  {
#pragma unroll
    for (int mt = 0; mt < 4; ++mt)
#pragma unroll
      for (int rg = 0; rg < 4; ++rg) {
        int row = mt * 16 + q * 4 + rg;
        XA[row * XS + col0] = f2b(acc[mt][0][rg]);
        XA[row * XS + col1] = f2b(acc[mt][1][rg]);
      }
  }
  if (tid < 64) egl[tid] = sigmoid_fast(gp[tid] + e_b[0]);
  BAR();   // m (bf16) + egl visible

  // ---- gated m_i PACKED f16 atomics: wave wv covers rows [16wv,16wv+16) ----
  // lane: j = uint idx within 64B chunk, rr = row within group-of-4.
  // per instruction: 4 rows x 1 cacheline = 4 line-visits (r7's proven shape),
  // 2 f16 adds per lane-op (half the lane-ops of f32).
  {
    int j = lane & 15, rr = lane >> 4;
#pragma unroll
    for (int rg = 0; rg < 4; ++rg) {
      int row = wv * 16 + rg * 4 + rr;
      float eg = egl[row];
      ushort* dst = outm + (size_t)erc[row] * 128;
      const uint* src = (const uint*)(XA + row * XS);
#pragma unroll
      for (int ch = 0; ch < 4; ++ch) {
        uint u = src[ch * 16 + j];
        float x = __uint_as_float(u << 16) * eg;           // bf16 lo
        float y = __uint_as_float(u & 0xffff0000u) * eg;   // bf16 hi
        pk_atomic_f16(dst + (ch * 16 + j) * 2, x, y);
      }
    }
  }

  // ---- phi_x layer 0: XA(m) -> acc (atomics above stay in flight) ----
#pragma unroll
  for (int mt = 0; mt < 4; ++mt) { acc[mt][0] = z4; acc[mt][1] = z4; }
  gemm2(XA, wq + 3 * 16384 + n0 * 128, c, q, acc);
  BAR();
  {
    float b0 = px_b0[col0], b1 = px_b0[col1];
#pragma unroll
    for (int mt = 0; mt < 4; ++mt)
#pragma unroll
      for (int rg = 0; rg < 4; ++rg) {
        int row = mt * 16 + q * 4 + rg;
        XA[row * XS + col0] = f2b(silu(acc[mt][0][rg] + b0));
        XA[row * XS + col1] = f2b(silu(acc[mt][1][rg] + b1));
      }
  }
  BAR();

  // ---- phi_x layer 1: XA -> Dense(1) tail ----
#pragma unroll
  for (int mt = 0; mt < 4; ++mt) { acc[mt][0] = z4; acc[mt][1] = z4; }
  gemm2(XA, wq + 4 * 16384 + n0 * 128, c, q, acc);
  {
    float b0 = px_b1[col0], b1 = px_b1[col1];
    float pw0 = px_out_w[col0], pw1 = px_out_w[col1];
#pragma unroll
    for (int mt = 0; mt < 4; ++mt)
#pragma unroll
      for (int rg = 0; rg < 4; ++rg) {
        float rp = silu(acc[mt][0][rg] + b0) * pw0 + silu(acc[mt][1][rg] + b1) * pw1;
        rp += __shfl_xor(rp, 1); rp += __shfl_xor(rp, 2);
        rp += __shfl_xor(rp, 4); rp += __shfl_xor(rp, 8);
        if (c == 0) atomicAdd(&pp[mt * 16 + q * 4 + rg], rp);
      }
  }
  BAR();
  if (tid < 192) {
    int ee = tid / 3, cc = tid - ee * 3;
    float phi = pp[ee] + px_out_b[0];
    float sh = phi * vec3[ee][cc] * __builtin_amdgcn_rcpf(1.0f + lenf[ee]);
    atomicAdd(&outv[(size_t)erc[ee] * 3 + cc], sh);
  }
}

// ---------------- node kernel: m_acc f16 in, residual from featb ----------------
__global__ __launch_bounds__(256, 3) void node_kernel(
    const float* __restrict__ pos,
    const ushort* __restrict__ featb, const ushort* __restrict__ wq,
    const ushort* __restrict__ outm,
    const float* __restrict__ ph_b0, const float* __restrict__ ph_b1,
    const float* __restrict__ ph_b2,
    float* __restrict__ outv, float* __restrict__ outf) {
  __shared__ ushort XA[64 * XS];
  __shared__ ushort XB[64 * XS];

  const int tid = threadIdx.x;
  const int nb0 = blockIdx.x * 64;
  const int lane = tid & 63;
  const int wv = tid >> 6;
  const int c = lane & 15, q = lane >> 4;
  const int n0 = wv * 32;
  const int col0 = n0 + c, col1 = col0 + 16;

  {
    int row = tid >> 2, sub = tid & 3;
    int nn = nb0 + row; if (nn >= N_NODES) nn = N_NODES - 1;
    stage_cvt_f16(XA, outm + (size_t)nn * 128, row, sub, INV_SQRT_AVG);  // m_i (f16)
    stage_copy(XB, featb + (size_t)nn * 128, row, sub);
  }
  BAR();

  const f32x4 z4 = {0.f, 0.f, 0.f, 0.f};
  f32x4 acc[4][2];
#pragma unroll
  for (int mt = 0; mt < 4; ++mt) { acc[mt][0] = z4; acc[mt][1] = z4; }

  // ---- ph layer 0: [m_i | feat] ----
  gemm2(XA, wq + 5 * 16384 + n0 * 128, c, q, acc);
  gemm2(XB, wq + 6 * 16384 + n0 * 128, c, q, acc);
  BAR();
  {
    float b0 = ph_b0[col0], b1 = ph_b0[col1];
#pragma unroll
    for (int mt = 0; mt < 4; ++mt)
#pragma unroll
      for (int rg = 0; rg < 4; ++rg) {
        int row = mt * 16 + q * 4 + rg;
        XA[row * XS + col0] = f2b(silu(acc[mt][0][rg] + b0));
        XA[row * XS + col1] = f2b(silu(acc[mt][1][rg] + b1));
      }
  }
  BAR();

  // ---- ph layer 1: XA -> XB (keep feat in XB? no: overwrite after reading) ----
#pragma unroll
  for (int mt = 0; mt < 4; ++mt) { acc[mt][0] = z4; acc[mt][1] = z4; }
  gemm2(XA, wq + 7 * 16384 + n0 * 128, c, q, acc);
  BAR();
  // stash residual source: XB still holds featb rows; we must keep them for the
  // final residual. Write h1 into XA instead (its h0 content is dead).
  {
    float b0 = ph_b1[col0], b1 = ph_b1[col1];
#pragma unroll
    for (int mt = 0; mt < 4; ++mt)
#pragma unroll
      for (int rg = 0; rg < 4; ++rg) {
        int row = mt * 16 + q * 4 + rg;
        XA[row * XS + col0] = f2b(silu(acc[mt][0][rg] + b0));
        XA[row * XS + col1] = f2b(silu(acc[mt][1][rg] + b1));
      }
  }
  BAR();

  // ---- ph layer 2 (no act) + residual from XB(featb) ----
#pragma unroll
  for (int mt = 0; mt < 4; ++mt) { acc[mt][0] = z4; acc[mt][1] = z4; }
  gemm2(XA, wq + 8 * 16384 + n0 * 128, c, q, acc);
  {
    float b0 = ph_b2[col0], b1 = ph_b2[col1];
#pragma unroll
    for (int mt = 0; mt < 4; ++mt)
#pragma unroll
      for (int rg = 0; rg < 4; ++rg) {
        int row = mt * 16 + q * 4 + rg;
        int nn = nb0 + row;
        if (nn < N_NODES) {
          size_t o = (size_t)nn * 128;
          float r0 = __uint_as_float(((uint)XB[row * XS + col0]) << 16);
          float r1 = __uint_as_float(((uint)XB[row * XS + col1]) << 16);
          outf[o + col0] = acc[mt][0][rg] + b0 + r0;
          outf[o + col1] = acc[mt][1][rg] + b1 + r1;
        }
      }
  }
  if (tid < 192) {
    int nl = tid / 3, cc = tid - nl * 3;
    int nn = nb0 + nl;
    if (nn < N_NODES)
      outv[nn * 3 + cc] = pos[nn * 3 + cc] + outv[nn * 3 + cc] * INV_AVG;
  }
}

// ---------------- launch ----------------
extern "C" void kernel_launch(void* const* d_in, const int* in_sizes, int n_in,
                              void* d_out, int out_size, void* d_ws, size_t ws_size,
                              hipStream_t stream) {
  const float* pos  = (const float*)d_in[0];
  const float* feat = (const float*)d_in[1];
  const float* pe_w0 = (const float*)d_in[2];
  const float* pe_b0 = (const float*)d_in[3];
  const float* pe_b1 = (const float*)d_in[5];
  const float* px_b0 = (const float*)d_in[7];
  const float* px_b1 = (const float*)d_in[9];
  const float* px_out_w = (const float*)d_in[10];
  const float* px_out_b = (const float*)d_in[11];
  const float* e_w = (const float*)d_in[12];
  const float* e_b = (const float*)d_in[13];
  const float* ph_b0 = (const float*)d_in[15];
  const float* ph_b1 = (const float*)d_in[17];
  const float* ph_b2 = (const float*)d_in[19];
  const int* snd = (const int*)d_in[20];
  const int* rcv = (const int*)d_in[21];
  ushort* wq = (ushort*)d_ws;
  ushort* featb = wq + FEATB_OFF;
  float* out = (float*)d_out;
  // after setup1 consumes feat, its buffer becomes the f16 m_i accumulator
  ushort* outm = (ushort*)d_in[1];

  PrepArgs a;
  a.src[0] = pe_w0;
  a.src[1] = pe_w0 + 128 * 128;
  a.src[2] = (const float*)d_in[4];               // pe_w1
  a.src[3] = (const float*)d_in[6];               // px_w0
  a.src[4] = (const float*)d_in[8];               // px_w1
  a.src[5] = (const float*)d_in[14];              // ph_w0 (m_i half)
  a.src[6] = (const float*)d_in[14] + 128 * 128;  // ph_w0 (feat half)
  a.src[7] = (const float*)d_in[16];              // ph_w1
  a.src[8] = (const float*)d_in[18];              // ph_w2

  // setup1: weight cvt + feat cvt + zero outv (reads all of feat)
  setup_kernel<<<(N_NODES * 128) / 256, 256, 0, stream>>>(a, feat, wq, featb, out);
  // setup2 (stream-ordered after setup1): zero f16 m_acc overlaying feat
  zero_macc_kernel<<<(N_NODES * 128 / 2) / 256, 256, 0, stream>>>((uint*)outm);

  edge_kernel<<<N_EDGES / 64, 256, 0, stream>>>(
      pos, featb, snd, rcv, wq,
      pe_w0, pe_b0, pe_b1, px_b0, px_b1,
      px_out_w, px_out_b, e_w, e_b,
      out, outm);

  node_kernel<<<(N_NODES + 63) / 64, 256, 0, stream>>>(
      pos, featb, wq, outm, ph_b0, ph_b1, ph_b2,
      out, out + 60000);
}